// Round 1
// baseline (2404.387 us; speedup 1.0000x reference)
//
#include <hip/hip_runtime.h>
#include <cstdint>
#include <cstddef>

#define TT 8192
#define HD 8
#define GG 32
#define IN2 16
#define ED 43
#define NL 64
#define OD 14
#define LCH 64
#define WU 64
#define NCH (TT / LCH)            // 128 chunks per direction
#define NBLK 64
#define NTHR 256
#define NWAVE (NBLK * NTHR / 64)  // 256 waves = NCH * 2

static_assert(NWAVE == 2 * NCH, "wave count must match chunk tasks");

// ws layout (float offsets)
#define WS_PRE0 0
#define WS_XBUF0 (TT * 2 * GG)
#define WS_XBUF1 (WS_XBUF0 + TT * IN2)
#define WS_BAR_F (WS_XBUF1 + TT * IN2)
#define WS_BAR_BYTE_OFF ((size_t)WS_BAR_F * 4)

template <int L>
__device__ __forceinline__ float rl(float x) {
  return __int_as_float(__builtin_amdgcn_readlane(__float_as_int(x), L));
}

template <int CTRL>
__device__ __forceinline__ float fdpp(float x) {
  return __int_as_float(
      __builtin_amdgcn_update_dpp(0, __float_as_int(x), CTRL, 0xF, 0xF, true));
}

__device__ __forceinline__ void grid_barrier(unsigned* bar) {
  __syncthreads();
  if (threadIdx.x == 0) {
    __threadfence();  // device-scope release of all prior writes (L2 writeback)
    unsigned old = __hip_atomic_fetch_add(bar, 1u, __ATOMIC_ACQ_REL,
                                          __HIP_MEMORY_SCOPE_AGENT);
    unsigned target = (old / NBLK + 1u) * NBLK;
    while (__hip_atomic_load(bar, __ATOMIC_ACQUIRE, __HIP_MEMORY_SCOPE_AGENT) <
           target) {
      __builtin_amdgcn_s_sleep(8);
    }
  }
  __syncthreads();
}

// One LSTM cell step. Lane q=4j+p owns gate p (0=i,1=f,2=g,3=o) of unit j.
// Weights/pre for p==2 rows are pre-scaled by 2 so a single uniform sigmoid
// pipeline computes both sigma and tanh: tanh(x) = 2*sigma(2x)-1.
__device__ __forceinline__ void lstm_step(float pcur, const float (&wh)[HD],
                                          float aa, float bb, float& h,
                                          float& c) {
  float a0 = fmaf(rl<0>(h), wh[0], pcur);
  a0 = fmaf(rl<4>(h), wh[1], a0);
  a0 = fmaf(rl<8>(h), wh[2], a0);
  a0 = fmaf(rl<12>(h), wh[3], a0);
  float a1 = rl<16>(h) * wh[4];
  a1 = fmaf(rl<20>(h), wh[5], a1);
  a1 = fmaf(rl<24>(h), wh[6], a1);
  a1 = fmaf(rl<28>(h), wh[7], a1);
  float z = a0 + a1;
  float e = __expf(-z);
  float r = __fdividef(1.0f, 1.0f + e);
  float y = fmaf(aa, r, bb);  // sigma(z) or tanh(z_nat)
  float iy = fdpp<0x00>(y);   // quad_perm broadcast slot 0
  float fy = fdpp<0x55>(y);   // slot 1
  float gy = fdpp<0xAA>(y);   // slot 2
  float oy = fdpp<0xFF>(y);   // slot 3
  c = fmaf(fy, c, iy * gy);
  float e2 = __expf(c * -2.0f);
  float th = fmaf(2.0f, __fdividef(1.0f, 1.0f + e2), -1.0f);  // tanh(c)
  h = oy * th;
}

__device__ __forceinline__ float dot16(const float (&x)[IN2],
                                       const float (&w)[IN2], float bias) {
  float a0 = bias, a1 = 0.f, a2 = 0.f, a3 = 0.f;
#pragma unroll
  for (int m = 0; m < 4; ++m) {
    a0 = fmaf(x[m], w[m], a0);
    a1 = fmaf(x[4 + m], w[4 + m], a1);
    a2 = fmaf(x[8 + m], w[8 + m], a2);
    a3 = fmaf(x[12 + m], w[12 + m], a3);
  }
  return (a0 + a1) + (a2 + a3);
}

__device__ __forceinline__ void loadx(float (&dst)[IN2],
                                      const float* __restrict__ xin, int t) {
  t = t < 0 ? 0 : (t > TT - 1 ? TT - 1 : t);
  const float4* p4 = (const float4*)(xin + (size_t)t * IN2);
  float4 a = p4[0], b = p4[1], cc = p4[2], d = p4[3];
  dst[0] = a.x; dst[1] = a.y; dst[2] = a.z; dst[3] = a.w;
  dst[4] = b.x; dst[5] = b.y; dst[6] = b.z; dst[7] = b.w;
  dst[8] = cc.x; dst[9] = cc.y; dst[10] = cc.z; dst[11] = cc.w;
  dst[12] = d.x; dst[13] = d.y; dst[14] = d.z; dst[15] = d.w;
}

__global__ __launch_bounds__(NTHR, 1) void lstm_all(
    const int* __restrict__ tok, const float* __restrict__ emb,
    const float* __restrict__ Wih0, const float* __restrict__ Whh0,
    const float* __restrict__ bih0, const float* __restrict__ bhh0,
    const float* __restrict__ Wih, const float* __restrict__ Whh,
    const float* __restrict__ bih, const float* __restrict__ bhh,
    const float* __restrict__ lin_w, const float* __restrict__ lin_b,
    float* __restrict__ out, float* __restrict__ ws) {
  float* pre0 = ws + WS_PRE0;   // [T][2][32] scaled pre-activations, layer 0
  float* xb0 = ws + WS_XBUF0;   // [T][16] layer output ping
  float* xb1 = ws + WS_XBUF1;   // pong
  unsigned* bar = (unsigned*)(ws + WS_BAR_F);

  const int tid = threadIdx.x;
  const int gtid = blockIdx.x * NTHR + tid;
  const int lane = tid & 63;

  // ---------------- Phase A0: layer-0 input projection ----------------
  __shared__ float s_w[2 * GG * ED];
  __shared__ float s_b[2 * GG];
  for (int i = tid; i < 2 * GG * ED; i += NTHR) {
    int d = i / (GG * ED);
    int rq = (i / ED) % GG;
    int m = i % ED;
    int p = rq & 3, j = rq >> 2;
    int k = p * 8 + j;  // PyTorch gate-row index
    float sc = (p == 2) ? 2.0f : 1.0f;
    s_w[i] = Wih0[((size_t)d * GG + k) * ED + m] * sc;
  }
  for (int i = tid; i < 2 * GG; i += NTHR) {
    int d = i / GG, rq = i % GG;
    int p = rq & 3, j = rq >> 2;
    int k = p * 8 + j;
    float sc = (p == 2) ? 2.0f : 1.0f;
    s_b[i] = (bih0[d * GG + k] + bhh0[d * GG + k]) * sc;
  }
  __syncthreads();
  if (gtid < TT) {
    int t = gtid;
    float xr[ED];
    const float* er = emb + (size_t)tok[t] * ED;
#pragma unroll
    for (int m = 0; m < ED; ++m) xr[m] = er[m];
    for (int d = 0; d < 2; ++d) {
      for (int rq = 0; rq < GG; ++rq) {
        const float* wr = s_w + ((size_t)d * GG + rq) * ED;
        float acc0 = s_b[d * GG + rq], acc1 = 0.f, acc2 = 0.f, acc3 = 0.f;
        int m = 0;
#pragma unroll
        for (; m + 4 <= ED; m += 4) {
          acc0 = fmaf(xr[m], wr[m], acc0);
          acc1 = fmaf(xr[m + 1], wr[m + 1], acc1);
          acc2 = fmaf(xr[m + 2], wr[m + 2], acc2);
          acc3 = fmaf(xr[m + 3], wr[m + 3], acc3);
        }
#pragma unroll
        for (; m < ED; ++m) acc0 = fmaf(xr[m], wr[m], acc0);
        pre0[((size_t)t * 2 + d) * GG + rq] = (acc0 + acc1) + (acc2 + acc3);
      }
    }
  }
  grid_barrier(bar);

  // ---------------- Scan setup: one wave per (chunk, dir) ----------------
  const int wave = gtid >> 6;
  const int dir = wave & 1;
  const int chunk = wave >> 1;
  const int q = lane & 31;       // lanes 32..63 mirror 0..31 (harmless)
  const int p = q & 3, jj = q >> 2;
  const int krow = p * 8 + jj;
  const float sc_row = (p == 2) ? 2.0f : 1.0f;
  const float aa = (p == 2) ? 2.0f : 1.0f;
  const float bb = (p == 2) ? -1.0f : 0.0f;
  const int keep0 = chunk * LCH, keep1 = keep0 + LCH;
  const int tstep = dir ? -1 : 1;
  int t0, nsteps;
  if (dir == 0) {
    t0 = keep0 - WU;
    if (t0 < 0) t0 = 0;
    nsteps = keep1 - t0;
  } else {
    t0 = keep1 - 1 + WU;
    if (t0 > TT - 1) t0 = TT - 1;
    nsteps = t0 - keep0 + 1;
  }

  for (int l = 0; l < NL; ++l) {
    const float* xin = (l & 1) ? xb0 : xb1;  // valid for l >= 1
    float* xout = (l & 1) ? xb1 : xb0;
    float wh[HD];
    {
      const float* whp =
          (l == 0) ? (Whh0 + ((size_t)dir * GG + krow) * HD)
                   : (Whh + (((size_t)(l - 1) * 2 + dir) * GG + krow) * HD);
#pragma unroll
      for (int m = 0; m < HD; ++m) wh[m] = whp[m] * sc_row;
    }
    float h = 0.f, c = 0.f;

    if (l == 0) {
      auto ldp = [&](int t) -> float {
        t = t < 0 ? 0 : (t > TT - 1 ? TT - 1 : t);
        return pre0[((size_t)t * 2 + dir) * GG + q];
      };
      float r0 = ldp(t0), r1 = ldp(t0 + tstep), r2 = ldp(t0 + 2 * tstep),
            r3 = ldp(t0 + 3 * tstep);
      int t = t0;
#define SUBSTEP0(PREG)                                                  \
  {                                                                     \
    float pc = PREG;                                                    \
    PREG = ldp(t + 4 * tstep);                                          \
    lstm_step(pc, wh, aa, bb, h, c);                                    \
    bool keep = (dir == 0) ? (t >= keep0) : (t < keep1);                \
    if (keep && (lane & 3) == 0 && lane < 32)                           \
      xout[(size_t)t * IN2 + dir * HD + jj] = h;                        \
    t += tstep;                                                         \
  }
#pragma unroll 1
      for (int i = 0; i < nsteps; i += 4) {
        SUBSTEP0(r0)
        SUBSTEP0(r1)
        SUBSTEP0(r2)
        SUBSTEP0(r3)
      }
#undef SUBSTEP0
    } else {
      float wi[IN2];
      float bias;
      {
        const size_t wbase = ((size_t)(l - 1) * 2 + dir) * GG + krow;
        const float* wip = Wih + wbase * IN2;
#pragma unroll
        for (int m = 0; m < IN2; ++m) wi[m] = wip[m] * sc_row;
        bias = (bih[wbase] + bhh[wbase]) * sc_row;
      }
      float xr0[IN2], xr1[IN2], xr2[IN2], xr3[IN2];
      loadx(xr0, xin, t0);
      loadx(xr1, xin, t0 + tstep);
      loadx(xr2, xin, t0 + 2 * tstep);
      loadx(xr3, xin, t0 + 3 * tstep);
      float pnext = dot16(xr0, wi, bias);
      int t = t0;
#define SUBSTEP(PSLOT, XSLOT)                                           \
  {                                                                     \
    float pc = pnext;                                                   \
    pnext = dot16(PSLOT, wi, bias);                                     \
    loadx(XSLOT, xin, t + 4 * tstep);                                   \
    lstm_step(pc, wh, aa, bb, h, c);                                    \
    bool keep = (dir == 0) ? (t >= keep0) : (t < keep1);                \
    if (keep && (lane & 3) == 0 && lane < 32)                           \
      xout[(size_t)t * IN2 + dir * HD + jj] = h;                        \
    t += tstep;                                                         \
  }
#pragma unroll 1
      for (int i = 0; i < nsteps; i += 4) {
        SUBSTEP(xr1, xr0)
        SUBSTEP(xr2, xr1)
        SUBSTEP(xr3, xr2)
        SUBSTEP(xr0, xr3)
      }
#undef SUBSTEP
    }
    grid_barrier(bar);
  }

  // ---------------- Final: linear + log_softmax ----------------
  if (gtid < TT) {
    int t = gtid;
    const float* xrp = (((NL - 1) & 1) ? xb1 : xb0) + (size_t)t * IN2;
    float xv[IN2];
#pragma unroll
    for (int m = 0; m < IN2; ++m) xv[m] = xrp[m];
    float zz[OD];
#pragma unroll
    for (int o = 0; o < OD; ++o) {
      const float* wr = lin_w + o * IN2;
      float a0 = lin_b[o], a1 = 0.f, a2 = 0.f, a3 = 0.f;
#pragma unroll
      for (int m = 0; m < 4; ++m) {
        a0 = fmaf(xv[m], wr[m], a0);
        a1 = fmaf(xv[4 + m], wr[4 + m], a1);
        a2 = fmaf(xv[8 + m], wr[8 + m], a2);
        a3 = fmaf(xv[12 + m], wr[12 + m], a3);
      }
      zz[o] = (a0 + a1) + (a2 + a3);
    }
    float mx = zz[0];
#pragma unroll
    for (int o = 1; o < OD; ++o) mx = fmaxf(mx, zz[o]);
    float s = 0.f;
#pragma unroll
    for (int o = 0; o < OD; ++o) s += __expf(zz[o] - mx);
    float lse = __logf(s);
#pragma unroll
    for (int o = 0; o < OD; ++o) out[(size_t)t * OD + o] = zz[o] - mx - lse;
  }
}

extern "C" void kernel_launch(void* const* d_in, const int* in_sizes, int n_in,
                              void* d_out, int out_size, void* d_ws,
                              size_t ws_size, hipStream_t stream) {
  const int* tok = (const int*)d_in[0];
  const float* emb = (const float*)d_in[1];
  const float* Wih0 = (const float*)d_in[2];
  const float* Whh0 = (const float*)d_in[3];
  const float* bih0 = (const float*)d_in[4];
  const float* bhh0 = (const float*)d_in[5];
  const float* Wih = (const float*)d_in[6];
  const float* Whh = (const float*)d_in[7];
  const float* bih = (const float*)d_in[8];
  const float* bhh = (const float*)d_in[9];
  const float* lin_w = (const float*)d_in[10];
  const float* lin_b = (const float*)d_in[11];

  // zero the grid-barrier counter (ws is poisoned 0xAA before every launch)
  hipMemsetAsync((char*)d_ws + WS_BAR_BYTE_OFF, 0, 64, stream);
  hipLaunchKernelGGL(lstm_all, dim3(NBLK), dim3(NTHR), 0, stream, tok, emb,
                     Wih0, Whh0, bih0, bhh0, Wih, Whh, bih, bhh, lin_w, lin_b,
                     (float*)d_out, (float*)d_ws);
}

// Round 3
// 1711.271 us; speedup vs baseline: 1.4050x; 1.4050x over previous
//
#include <hip/hip_runtime.h>
#include <cstdint>
#include <cstddef>

#define TT 8192
#define HD 8
#define GG 32
#define IN2 16
#define ED 43
#define NL 64
#define OD 14
#define LCH 16
#define WU 32
#define WIN (LCH + WU)            // 48 rows staged per task
#define NCH (TT / LCH)            // 512 chunks per direction
#define NBLK 256
#define NTHR 256
#define TPB 4                     // tasks (waves) per block
#define NWAVE (NBLK * NTHR / 64)  // 1024 waves = NCH*2 tasks

static_assert(NWAVE == 2 * NCH, "wave count must match chunk tasks");

#define L2E 1.44269504088896340736f
#define M2L2E 2.88539008177792680f  // 2*log2(e)

// ws layout (float offsets)
#define WS_PRE0 0
#define WS_XBUF0 (TT * 2 * GG)
#define WS_XBUF1 (WS_XBUF0 + TT * IN2)
#define WS_BAR_F (WS_XBUF1 + TT * IN2)
#define WS_BAR_BYTE_OFF ((size_t)WS_BAR_F * 4)

template <int L>
__device__ __forceinline__ float rl(float x) {
  return __int_as_float(__builtin_amdgcn_readlane(__float_as_int(x), L));
}

template <int CTRL>
__device__ __forceinline__ float fdpp(float x) {
  return __int_as_float(
      __builtin_amdgcn_update_dpp(0, __float_as_int(x), CTRL, 0xF, 0xF, true));
}

__device__ __forceinline__ float ex2(float x) {
#if __has_builtin(__builtin_amdgcn_exp2f)
  return __builtin_amdgcn_exp2f(x);
#else
  return exp2f(x);
#endif
}

__device__ __forceinline__ float frcp(float x) {
  return __builtin_amdgcn_rcpf(x);
}

__device__ __forceinline__ void grid_barrier(unsigned* bar) {
  __syncthreads();
  if (threadIdx.x == 0) {
    __threadfence();  // device-scope release (cross-XCD visibility of xbuf)
    unsigned old = __hip_atomic_fetch_add(bar, 1u, __ATOMIC_ACQ_REL,
                                          __HIP_MEMORY_SCOPE_AGENT);
    unsigned target = (old / NBLK + 1u) * NBLK;
    while (__hip_atomic_load(bar, __ATOMIC_ACQUIRE, __HIP_MEMORY_SCOPE_AGENT) <
           target) {
      __builtin_amdgcn_s_sleep(4);
    }
  }
  __syncthreads();
}

// One LSTM cell step. Lane q=4j+p owns gate p (0=i,1=f,2=g,3=o) of unit j.
// All pre-activations/weights are pre-scaled by log2(e) (x2 for p==2 rows) so
// one uniform exp2+rcp pipeline yields sigma (p!=2) or tanh (p==2).
__device__ __forceinline__ void lstm_step(float pcur, const float (&wh)[HD],
                                          float aa, float bb, float& h,
                                          float& c) {
  float a0 = fmaf(rl<0>(h), wh[0], pcur);
  a0 = fmaf(rl<4>(h), wh[1], a0);
  a0 = fmaf(rl<8>(h), wh[2], a0);
  a0 = fmaf(rl<12>(h), wh[3], a0);
  float a1 = rl<16>(h) * wh[4];
  a1 = fmaf(rl<20>(h), wh[5], a1);
  a1 = fmaf(rl<24>(h), wh[6], a1);
  a1 = fmaf(rl<28>(h), wh[7], a1);
  float z = a0 + a1;                 // log2-domain pre-activation
  float r = frcp(1.0f + ex2(-z));
  float y = fmaf(aa, r, bb);         // sigma(z) or tanh(z_nat)
  float iy = fdpp<0x00>(y);          // quad_perm broadcast slot 0
  float fy = fdpp<0x55>(y);          // slot 1
  float gy = fdpp<0xAA>(y);          // slot 2
  float oy = fdpp<0xFF>(y);          // slot 3
  c = fmaf(fy, c, iy * gy);
  float th = fmaf(2.0f, frcp(1.0f + ex2(c * -M2L2E)), -1.0f);  // tanh(c)
  h = oy * th;
}

__device__ __forceinline__ float dot16(const float (&x)[IN2],
                                       const float (&w)[IN2], float bias) {
  float a0 = bias, a1 = 0.f, a2 = 0.f, a3 = 0.f;
#pragma unroll
  for (int m = 0; m < 4; ++m) {
    a0 = fmaf(x[m], w[m], a0);
    a1 = fmaf(x[4 + m], w[4 + m], a1);
    a2 = fmaf(x[8 + m], w[8 + m], a2);
    a3 = fmaf(x[12 + m], w[12 + m], a3);
  }
  return (a0 + a1) + (a2 + a3);
}

__global__ __launch_bounds__(NTHR, 1) void lstm_all(
    const int* __restrict__ tok, const float* __restrict__ emb,
    const float* __restrict__ Wih0, const float* __restrict__ Whh0,
    const float* __restrict__ bih0, const float* __restrict__ bhh0,
    const float* __restrict__ Wih, const float* __restrict__ Whh,
    const float* __restrict__ bih, const float* __restrict__ bhh,
    const float* __restrict__ lin_w, const float* __restrict__ lin_b,
    float* __restrict__ out, float* __restrict__ ws) {
  float* pre0 = ws + WS_PRE0;   // [T][2][32] scaled pre-activations, layer 0
  float* xb0 = ws + WS_XBUF0;   // [T][16] layer output ping
  float* xb1 = ws + WS_XBUF1;   // pong
  unsigned* bar = (unsigned*)(ws + WS_BAR_F);

  const int tid = threadIdx.x;
  const int gtid = blockIdx.x * NTHR + tid;
  const int lane = tid & 63;

  __shared__ float s_w[2 * GG * ED];
  __shared__ float s_b[2 * GG];
  __shared__ alignas(16) float s_stage[TPB * WIN * GG];  // 24 KB (x uses 12)

  // ---------------- Phase A0: layer-0 input projection ----------------
  for (int i = tid; i < 2 * GG * ED; i += NTHR) {
    int d = i / (GG * ED);
    int rq = (i / ED) % GG;
    int m = i % ED;
    int p = rq & 3, j = rq >> 2;
    int k = p * 8 + j;  // PyTorch gate-row index
    float sc = ((p == 2) ? 2.0f : 1.0f) * L2E;
    s_w[i] = Wih0[((size_t)d * GG + k) * ED + m] * sc;
  }
  for (int i = tid; i < 2 * GG; i += NTHR) {
    int d = i / GG, rq = i % GG;
    int p = rq & 3, j = rq >> 2;
    int k = p * 8 + j;
    float sc = ((p == 2) ? 2.0f : 1.0f) * L2E;
    s_b[i] = (bih0[d * GG + k] + bhh0[d * GG + k]) * sc;
  }
  __syncthreads();
  {
    // 65536 threads == TT*8 units: each computes 8 of the 64 (dir,row) dots.
    int t = gtid >> 3;
    int r8 = gtid & 7;
    float xr[ED];
    const float* er = emb + (size_t)tok[t] * ED;
#pragma unroll
    for (int m = 0; m < ED; ++m) xr[m] = er[m];
#pragma unroll
    for (int rr = 0; rr < 8; ++rr) {
      int dr = r8 * 8 + rr;
      int d = dr >> 5, rq = dr & 31;
      const float* wr = s_w + ((size_t)d * GG + rq) * ED;
      float acc0 = s_b[d * GG + rq], acc1 = 0.f, acc2 = 0.f, acc3 = 0.f;
      int m = 0;
#pragma unroll
      for (; m + 4 <= ED; m += 4) {
        acc0 = fmaf(xr[m], wr[m], acc0);
        acc1 = fmaf(xr[m + 1], wr[m + 1], acc1);
        acc2 = fmaf(xr[m + 2], wr[m + 2], acc2);
        acc3 = fmaf(xr[m + 3], wr[m + 3], acc3);
      }
#pragma unroll
      for (; m < ED; ++m) acc0 = fmaf(xr[m], wr[m], acc0);
      pre0[((size_t)t * 2 + d) * GG + rq] = (acc0 + acc1) + (acc2 + acc3);
    }
  }
  grid_barrier(bar);

  // ---------------- Scan setup: one wave per (chunk, dir) ----------------
  const int wave = gtid >> 6;
  const int dir = wave & 1;
  const int chunk = wave >> 1;
  const int task = tid >> 6;     // wave index within block
  const int q = lane & 31;       // lanes 32..63 mirror 0..31 (harmless)
  const int p = q & 3, jj = q >> 2;
  const int krow = p * 8 + jj;
  const float sc_row = ((p == 2) ? 2.0f : 1.0f) * L2E;
  const float aa = (p == 2) ? 2.0f : 1.0f;
  const float bb = (p == 2) ? -1.0f : 0.0f;
  const int keep0 = chunk * LCH, keep1 = keep0 + LCH;
  const int tstep = dir ? -1 : 1;
  int t0, nsteps;
  if (dir == 0) {
    t0 = keep0 - WU;
    if (t0 < 0) t0 = 0;
    nsteps = keep1 - t0;
  } else {
    t0 = keep1 - 1 + WU;
    if (t0 > TT - 1) t0 = TT - 1;
    nsteps = t0 - keep0 + 1;
  }
  const int skeep = nsteps - LCH;  // step index from which outputs are kept

  for (int l = 0; l < NL; ++l) {
    const float* xin = (l & 1) ? xb0 : xb1;  // valid for l >= 1
    float* xout = (l & 1) ? xb1 : xb0;
    float wh[HD];
    {
      const float* whp =
          (l == 0) ? (Whh0 + ((size_t)dir * GG + krow) * HD)
                   : (Whh + (((size_t)(l - 1) * 2 + dir) * GG + krow) * HD);
#pragma unroll
      for (int m = 0; m < HD; ++m) wh[m] = whp[m] * sc_row;
    }
    float h = 0.f, c = 0.f;

    // ---- cooperative LDS staging of each task's window (step order) ----
    if (l == 0) {
      for (int i = tid; i < TPB * WIN * (GG / 4); i += NTHR) {
        int tk = i / (WIN * 8);
        int rem = i % (WIN * 8);
        int row = rem / 8, c4 = rem % 8;
        int wg = blockIdx.x * TPB + tk;
        int dS = wg & 1, cS = wg >> 1;
        int k0 = cS * LCH;
        int t0S, tsS;
        if (dS == 0) {
          t0S = k0 - WU; if (t0S < 0) t0S = 0; tsS = 1;
        } else {
          t0S = k0 + LCH - 1 + WU; if (t0S > TT - 1) t0S = TT - 1; tsS = -1;
        }
        int t = t0S + row * tsS;
        t = t < 0 ? 0 : (t > TT - 1 ? TT - 1 : t);
        const float4 v =
            *(const float4*)(pre0 + ((size_t)t * 2 + dS) * GG + c4 * 4);
        *(float4*)(s_stage + ((size_t)tk * WIN + row) * GG + c4 * 4) = v;
      }
    } else {
      for (int i = tid; i < TPB * WIN * (IN2 / 4); i += NTHR) {
        int tk = i / (WIN * 4);
        int rem = i % (WIN * 4);
        int row = rem / 4, c4 = rem % 4;
        int wg = blockIdx.x * TPB + tk;
        int dS = wg & 1, cS = wg >> 1;
        int k0 = cS * LCH;
        int t0S, tsS;
        if (dS == 0) {
          t0S = k0 - WU; if (t0S < 0) t0S = 0; tsS = 1;
        } else {
          t0S = k0 + LCH - 1 + WU; if (t0S > TT - 1) t0S = TT - 1; tsS = -1;
        }
        int t = t0S + row * tsS;
        t = t < 0 ? 0 : (t > TT - 1 ? TT - 1 : t);
        const float4 v = *(const float4*)(xin + (size_t)t * IN2 + c4 * 4);
        *(float4*)(s_stage + ((size_t)tk * WIN + row) * IN2 + c4 * 4) = v;
      }
    }
    __syncthreads();

    if (l == 0) {
      const float* sp = s_stage + (size_t)task * WIN * GG;
      auto ldp = [&](int s) -> float {
        s = s > WIN - 1 ? WIN - 1 : s;
        return sp[s * GG + q];
      };
      float r0 = ldp(0), r1 = ldp(1), r2 = ldp(2), r3 = ldp(3);
      int t = t0, s = 0;
#define SUBSTEP0(PREG)                                                  \
  {                                                                     \
    float pc = PREG;                                                    \
    PREG = ldp(s + 4);                                                  \
    lstm_step(pc, wh, aa, bb, h, c);                                    \
    if (s >= skeep && (lane & 3) == 0 && lane < 32)                     \
      xout[(size_t)t * IN2 + dir * HD + jj] = h;                        \
    t += tstep; ++s;                                                    \
  }
#pragma unroll 1
      for (int i = 0; i < nsteps; i += 4) {
        SUBSTEP0(r0)
        SUBSTEP0(r1)
        SUBSTEP0(r2)
        SUBSTEP0(r3)
      }
#undef SUBSTEP0
    } else {
      float wi[IN2];
      float bias;
      {
        const size_t wbase = ((size_t)(l - 1) * 2 + dir) * GG + krow;
        const float* wip = Wih + wbase * IN2;
#pragma unroll
        for (int m = 0; m < IN2; ++m) wi[m] = wip[m] * sc_row;
        bias = (bih[wbase] + bhh[wbase]) * sc_row;
      }
      const float* sxw = s_stage + (size_t)task * WIN * IN2;
      auto ldx = [&](float (&dst)[IN2], int s) {
        s = s > WIN - 1 ? WIN - 1 : s;
        const float4* p4 = (const float4*)(sxw + s * IN2);
        float4 a = p4[0], b = p4[1], cc = p4[2], d = p4[3];
        dst[0] = a.x; dst[1] = a.y; dst[2] = a.z; dst[3] = a.w;
        dst[4] = b.x; dst[5] = b.y; dst[6] = b.z; dst[7] = b.w;
        dst[8] = cc.x; dst[9] = cc.y; dst[10] = cc.z; dst[11] = cc.w;
        dst[12] = d.x; dst[13] = d.y; dst[14] = d.z; dst[15] = d.w;
      };
      float xr0[IN2], xr1[IN2], xr2[IN2], xr3[IN2];
      ldx(xr0, 0); ldx(xr1, 1); ldx(xr2, 2); ldx(xr3, 3);
      float pnext = dot16(xr0, wi, bias);
      int t = t0, s = 0;
#define SUBSTEP(PSLOT, XSLOT)                                           \
  {                                                                     \
    float pc = pnext;                                                   \
    pnext = dot16(PSLOT, wi, bias);                                     \
    ldx(XSLOT, s + 4);                                                  \
    lstm_step(pc, wh, aa, bb, h, c);                                    \
    if (s >= skeep && (lane & 3) == 0 && lane < 32)                     \
      xout[(size_t)t * IN2 + dir * HD + jj] = h;                        \
    t += tstep; ++s;                                                    \
  }
#pragma unroll 1
      for (int i = 0; i < nsteps; i += 4) {
        SUBSTEP(xr1, xr0)
        SUBSTEP(xr2, xr1)
        SUBSTEP(xr3, xr2)
        SUBSTEP(xr0, xr3)
      }
#undef SUBSTEP
    }
    grid_barrier(bar);
  }

  // ---------------- Final: linear + log_softmax ----------------
  if (gtid < TT) {
    int t = gtid;
    const float* xrp = (((NL - 1) & 1) ? xb1 : xb0) + (size_t)t * IN2;
    float xv[IN2];
#pragma unroll
    for (int m = 0; m < IN2; ++m) xv[m] = xrp[m];
    float zz[OD];
#pragma unroll
    for (int o = 0; o < OD; ++o) {
      const float* wr = lin_w + o * IN2;
      float a0 = lin_b[o], a1 = 0.f, a2 = 0.f, a3 = 0.f;
#pragma unroll
      for (int m = 0; m < 4; ++m) {
        a0 = fmaf(xv[m], wr[m], a0);
        a1 = fmaf(xv[4 + m], wr[4 + m], a1);
        a2 = fmaf(xv[8 + m], wr[8 + m], a2);
        a3 = fmaf(xv[12 + m], wr[12 + m], a3);
      }
      zz[o] = (a0 + a1) + (a2 + a3);
    }
    float mx = zz[0];
#pragma unroll
    for (int o = 1; o < OD; ++o) mx = fmaxf(mx, zz[o]);
    float s = 0.f;
#pragma unroll
    for (int o = 0; o < OD; ++o) s += __expf(zz[o] - mx);
    float lse = __logf(s);
#pragma unroll
    for (int o = 0; o < OD; ++o) out[(size_t)t * OD + o] = zz[o] - mx - lse;
  }
}

extern "C" void kernel_launch(void* const* d_in, const int* in_sizes, int n_in,
                              void* d_out, int out_size, void* d_ws,
                              size_t ws_size, hipStream_t stream) {
  const int* tok = (const int*)d_in[0];
  const float* emb = (const float*)d_in[1];
  const float* Wih0 = (const float*)d_in[2];
  const float* Whh0 = (const float*)d_in[3];
  const float* bih0 = (const float*)d_in[4];
  const float* bhh0 = (const float*)d_in[5];
  const float* Wih = (const float*)d_in[6];
  const float* Whh = (const float*)d_in[7];
  const float* bih = (const float*)d_in[8];
  const float* bhh = (const float*)d_in[9];
  const float* lin_w = (const float*)d_in[10];
  const float* lin_b = (const float*)d_in[11];

  // zero the grid-barrier counter (ws is poisoned 0xAA before every launch)
  (void)hipMemsetAsync((char*)d_ws + WS_BAR_BYTE_OFF, 0, 64, stream);
  hipLaunchKernelGGL(lstm_all, dim3(NBLK), dim3(NTHR), 0, stream, tok, emb,
                     Wih0, Whh0, bih0, bhh0, Wih, Whh, bih, bhh, lin_w, lin_b,
                     (float*)d_out, (float*)d_ws);
}